// Round 10
// baseline (55.452 us; speedup 1.0000x reference)
//
#include <hip/hip_runtime.h>
#include <math.h>

#define EPS 1e-8f
#define NPATCH 196
#define HW 50176
#define LOG2E 1.4426950408889634f

// ws float offsets
#define COUNT_OFF 0        // 1 int ticket counter
#define P5T_OFF 64         // [gp][48]      norm^2 partials, patch-major
#define DJT_OFF 40960      // [gp][48][4]   basis-dot partials, patch-major
#define PART_OFF 196608    // 392           per-block pixel partials
#define WA_OFF 212992      // bf16[768*768]  (147456 float slots)
#define XPB_OFF 360448     // bf16[784*768]  (150528 float slots)

typedef __attribute__((ext_vector_type(8))) short short8;
typedef __attribute__((ext_vector_type(4))) float f32x4;

static __device__ __forceinline__ unsigned short f2bf(float f) {
    unsigned u = __float_as_uint(f);
    u += 0x8000u + ((u >> 16) & 1u);     // RNE
    return (unsigned short)(u >> 16);
}

// ---- prep: pure streaming bf16 conversion ----
// blocks 0..287: WA = bf16(paw); blocks 288..581: XPB = bf16(gathered x)
__global__ __launch_bounds__(256) void k_prep(const float* __restrict__ x,
                                              const float* __restrict__ paw,
                                              float* __restrict__ ws) {
    int t = threadIdx.x;
    int bid = blockIdx.x;
    if (bid == 0 && t == 0) *(int*)(ws + COUNT_OFF) = 0;   // ticket reset
    if (bid < 288) {
        int f8 = bid * 256 + t;                    // 0..73727
        const float4* src = (const float4*)paw + (size_t)f8 * 2;
        float4 a = src[0], b = src[1];
        short8 o;
        o[0] = f2bf(a.x); o[1] = f2bf(a.y); o[2] = f2bf(a.z); o[3] = f2bf(a.w);
        o[4] = f2bf(b.x); o[5] = f2bf(b.y); o[6] = f2bf(b.z); o[7] = f2bf(b.w);
        *(short8*)((unsigned short*)(ws + WA_OFF) + (size_t)f8 * 8) = o;
    } else {
        int f8 = (bid - 288) * 256 + t;            // 0..75263
        int gp = f8 / 96;                          // 96 8-chunks per patch
        int e = (f8 - gp * 96) * 8;
        int b = gp / NPATCH, m = gp - b * NPATCH;
        int hp = m / 14, wq = m - hp * 14;
        int c = e >> 8, rem = e & 255, pr = rem >> 4, q0 = rem & 15;
        const float* src = x + ((size_t)(b * 3 + c) * 224 + hp * 16 + pr) * 224
                             + wq * 16 + q0;
        float4 a = *(const float4*)src;
        float4 b2 = *(const float4*)(src + 4);
        short8 o;
        o[0] = f2bf(a.x);  o[1] = f2bf(a.y);  o[2] = f2bf(a.z);  o[3] = f2bf(a.w);
        o[4] = f2bf(b2.x); o[5] = f2bf(b2.y); o[6] = f2bf(b2.z); o[7] = f2bf(b2.w);
        *(short8*)((unsigned short*)(ws + XPB_OFF) + (size_t)gp * 768 + e) = o;
    }
}

// 588 blocks x 256 (4 waves). wave -> one 16x16 C tile, K=768 in 24 MFMA.
// bf16 inputs from WA/XPB; emits patch-major per-(patch,mtile) partials.
__global__ __launch_bounds__(256) void k_gemm(const float* __restrict__ pixw,
                                              const float* __restrict__ pixb,
                                              const float* __restrict__ pab,
                                              float* __restrict__ ws) {
    const unsigned short* WA  = (const unsigned short*)(ws + WA_OFF);
    const unsigned short* XPB = (const unsigned short*)(ws + XPB_OFF);
    int t = threadIdx.x;
    int lane = t & 63, wv = t >> 6;
    int bid = blockIdx.x;
    int msup = bid / 49;
    int ntile = bid - msup * 49;
    int mtile = msup * 4 + wv;
    int m0 = mtile * 16, n0 = ntile * 16;
    int ra = lane & 15, kg = lane >> 4;
    const short8* pa = (const short8*)(WA  + (size_t)(m0 + ra) * 768 + kg * 8);
    const short8* pb = (const short8*)(XPB + (size_t)(n0 + ra) * 768 + kg * 8);
    f32x4 acc = {0.f, 0.f, 0.f, 0.f};
    #pragma unroll 6
    for (int kk = 0; kk < 24; ++kk) {
        short8 a = pa[kk * 4];
        short8 b = pb[kk * 4];
        acc = __builtin_amdgcn_mfma_f32_16x16x32_bf16(a, b, acc, 0, 0, 0);
    }
    // C[row][col]: col = lane&15 (patch), row = kg*4 + i (dim in tile)
    float sq = 0.f, d0 = 0.f, d1 = 0.f, d2 = 0.f, d3 = 0.f;
    #pragma unroll
    for (int i = 0; i < 4; ++i) {
        int d = m0 + kg * 4 + i;
        float v = acc[i] + pab[d];
        sq = fmaf(v, v, sq);
        d0 = fmaf(pixw[d*3+0], v, d0);
        d1 = fmaf(pixw[d*3+1], v, d1);
        d2 = fmaf(pixw[d*3+2], v, d2);
        d3 = fmaf(pixb[d],     v, d3);
    }
    sq += __shfl_down(sq, 32); d0 += __shfl_down(d0, 32);
    d1 += __shfl_down(d1, 32); d2 += __shfl_down(d2, 32);
    d3 += __shfl_down(d3, 32);
    sq += __shfl_down(sq, 16); d0 += __shfl_down(d0, 16);
    d1 += __shfl_down(d1, 16); d2 += __shfl_down(d2, 16);
    d3 += __shfl_down(d3, 16);
    if (lane < 16) {
        int g = n0 + lane;
        ws[P5T_OFF + (size_t)g * 48 + mtile] = sq;                 // patch-major
        *(float4*)&ws[DJT_OFF + ((size_t)g * 48 + mtile) * 4] =
            make_float4(d0, d1, d2, d3);
    }
}

// 392 blocks x 256, 2 pixels/thread: gram + GQ finalize (LDS) + exp-sums;
// last block (device ticket) reduces all 392 partials in fixed order + log.
__global__ __launch_bounds__(256) void k_pixel(const float* __restrict__ x,
                                               const float* __restrict__ pixw,
                                               const float* __restrict__ pixb,
                                               float* __restrict__ ws,
                                               float* __restrict__ out) {
    __shared__ float gtmp[4][10];
    __shared__ float gram_s[10];
    __shared__ float raw[NPATCH][5];
    __shared__ float gq[NPATCH][4];
    __shared__ float red[4];
    __shared__ int is_last;
    int t = threadIdx.x;
    int bid = blockIdx.x;
    int b = bid / 98;

    // ---- gram (10 floats), per-block (L2-hot broadcast) ----
    {
        float g[10];
        #pragma unroll
        for (int j = 0; j < 10; ++j) g[j] = 0.f;
        #pragma unroll
        for (int dd = 0; dd < 3; ++dd) {
            int d = t + dd * 256;
            float w0 = pixw[d*3+0], w1 = pixw[d*3+1], w2 = pixw[d*3+2], bb = pixb[d];
            g[0] = fmaf(w0, w0, g[0]); g[1] = fmaf(w0, w1, g[1]);
            g[2] = fmaf(w0, w2, g[2]); g[3] = fmaf(w0, bb, g[3]);
            g[4] = fmaf(w1, w1, g[4]); g[5] = fmaf(w1, w2, g[5]);
            g[6] = fmaf(w1, bb, g[6]); g[7] = fmaf(w2, w2, g[7]);
            g[8] = fmaf(w2, bb, g[8]); g[9] = fmaf(bb, bb, g[9]);
        }
        #pragma unroll
        for (int off = 32; off; off >>= 1)
            #pragma unroll
            for (int j = 0; j < 10; ++j) g[j] += __shfl_down(g[j], off);
        int wvv = t >> 6, ln = t & 63;
        if (ln == 0)
            #pragma unroll
            for (int j = 0; j < 10; ++j) gtmp[wvv][j] = g[j];
    }

    // ---- GQ: contiguous patch-major reduction (2 passes of 256 lanes) ----
    #pragma unroll
    for (int tt = t; tt < 392; tt += 256) {
        int p = tt >> 1, h = tt & 1;
        int g = b * NPATCH + p;
        const float*  p5 = ws + P5T_OFF + (size_t)g * 48 + h * 24;
        const float4* dj = (const float4*)(ws + DJT_OFF) + (size_t)g * 48 + h * 24;
        float n2 = 0.f, e0 = 0.f, e1 = 0.f, e2 = 0.f, e3 = 0.f;
        #pragma unroll 8
        for (int i = 0; i < 24; ++i) {
            n2 += p5[i];
            float4 v = dj[i];
            e0 += v.x; e1 += v.y; e2 += v.z; e3 += v.w;
        }
        n2 += __shfl_down(n2, 1); e0 += __shfl_down(e0, 1);
        e1 += __shfl_down(e1, 1); e2 += __shfl_down(e2, 1);
        e3 += __shfl_down(e3, 1);
        if (h == 0) {
            raw[p][0] = n2; raw[p][1] = e0; raw[p][2] = e1;
            raw[p][3] = e2; raw[p][4] = e3;
        }
    }
    __syncthreads();
    if (t < 10)
        gram_s[t] = gtmp[0][t] + gtmp[1][t] + gtmp[2][t] + gtmp[3][t];
    if (t < NPATCH) {
        float rq = 1.0f / fmaxf(sqrtf(raw[t][0]), EPS);
        gq[t][0] = raw[t][1] * rq;
        gq[t][1] = raw[t][2] * rq;
        gq[t][2] = raw[t][3] * rq;
        gq[t][3] = raw[t][4] * rq;
    }
    __syncthreads();

    // ---- pixel exp-sums: 2 pixels per thread ----
    int hw0 = (bid - b * 98) * 512 + t;
    int hw1 = hw0 + 256;
    const float* xb = x + (size_t)b * (3 * HW);
    float G0 = gram_s[0], G1 = gram_s[1], G2 = gram_s[2], G3 = gram_s[3];
    float G4 = gram_s[4], G5 = gram_s[5], G6 = gram_s[6], G7 = gram_s[7];
    float G8 = gram_s[8], G9 = gram_s[9];

    float p0a0, p0a1, p0a2, p0es, p1a0, p1a1, p1a2, p1es;
    {
        float c0 = xb[hw0], c1 = xb[hw0 + HW], c2 = xb[hw0 + 2 * HW];
        float n2 = G9;
        n2 = fmaf(G0, c0 * c0, n2); n2 = fmaf(G4, c1 * c1, n2);
        n2 = fmaf(G7, c2 * c2, n2);
        float cross = fmaf(G1, c0 * c1, fmaf(G2, c0 * c2, fmaf(G5, c1 * c2,
                      fmaf(G3, c0, fmaf(G6, c1, G8 * c2)))));
        n2 = fmaf(2.0f, cross, n2);
        float rnp = 1.0f / fmaxf(sqrtf(n2), EPS);
        p0es = 2.0f * rnp * LOG2E;
        p0a0 = c0 * p0es; p0a1 = c1 * p0es; p0a2 = c2 * p0es;
    }
    {
        float c0 = xb[hw1], c1 = xb[hw1 + HW], c2 = xb[hw1 + 2 * HW];
        float n2 = G9;
        n2 = fmaf(G0, c0 * c0, n2); n2 = fmaf(G4, c1 * c1, n2);
        n2 = fmaf(G7, c2 * c2, n2);
        float cross = fmaf(G1, c0 * c1, fmaf(G2, c0 * c2, fmaf(G5, c1 * c2,
                      fmaf(G3, c0, fmaf(G6, c1, G8 * c2)))));
        n2 = fmaf(2.0f, cross, n2);
        float rnp = 1.0f / fmaxf(sqrtf(n2), EPS);
        p1es = 2.0f * rnp * LOG2E;
        p1a0 = c0 * p1es; p1a1 = c1 * p1es; p1a2 = c2 * p1es;
    }

    float sum0 = 0.f, sum1 = 0.f;
    #pragma unroll 4
    for (int m = 0; m < NPATCH; ++m) {
        float4 g = *(const float4*)gq[m];
        float t0 = fmaf(p0a0, g.x, fmaf(p0a1, g.y, fmaf(p0a2, g.z, p0es * g.w)));
        float t1 = fmaf(p1a0, g.x, fmaf(p1a1, g.y, fmaf(p1a2, g.z, p1es * g.w)));
        sum0 += __builtin_amdgcn_exp2f(t0);
        sum1 += __builtin_amdgcn_exp2f(t1);
    }
    {
        int ne = hw0 % NPATCH;
        float4 g = *(const float4*)gq[ne];
        float t0 = fmaf(p0a0, g.x, fmaf(p0a1, g.y, fmaf(p0a2, g.z, p0es * g.w)));
        sum0 -= __builtin_amdgcn_exp2f(t0);
    }
    {
        int ne = hw1 % NPATCH;
        float4 g = *(const float4*)gq[ne];
        float t1 = fmaf(p1a0, g.x, fmaf(p1a1, g.y, fmaf(p1a2, g.z, p1es * g.w)));
        sum1 -= __builtin_amdgcn_exp2f(t1);
    }
    float sum = sum0 + sum1;
    #pragma unroll
    for (int off = 32; off; off >>= 1) sum += __shfl_down(sum, off);
    int wvv = t >> 6, ln = t & 63;
    if (ln == 0) red[wvv] = sum;
    __syncthreads();
    if (t == 0) {
        float s = red[0] + red[1] + red[2] + red[3];
        __hip_atomic_store(&ws[PART_OFF + bid], s, __ATOMIC_RELEASE,
                           __HIP_MEMORY_SCOPE_AGENT);
        int old = __hip_atomic_fetch_add((int*)(ws + COUNT_OFF), 1,
                                         __ATOMIC_ACQ_REL,
                                         __HIP_MEMORY_SCOPE_AGENT);
        is_last = (old == 391);
    }
    __syncthreads();

    // ---- last block: deterministic fixed-order reduce + log ----
    if (is_last) {
        float v = __hip_atomic_load(&ws[PART_OFF + t], __ATOMIC_ACQUIRE,
                                    __HIP_MEMORY_SCOPE_AGENT);
        if (t < 136)
            v += __hip_atomic_load(&ws[PART_OFF + t + 256], __ATOMIC_ACQUIRE,
                                   __HIP_MEMORY_SCOPE_AGENT);
        #pragma unroll
        for (int off = 32; off; off >>= 1) v += __shfl_down(v, off);
        __syncthreads();
        if ((t & 63) == 0) red[t >> 6] = v;
        __syncthreads();
        if (t == 0)
            out[0] = logf(red[0] + red[1] + red[2] + red[3]);
    }
}

extern "C" void kernel_launch(void* const* d_in, const int* in_sizes, int n_in,
                              void* d_out, int out_size, void* d_ws, size_t ws_size,
                              hipStream_t stream) {
    (void)in_sizes; (void)n_in; (void)out_size; (void)ws_size;
    const float* x    = (const float*)d_in[0];
    const float* pixw = (const float*)d_in[1];
    const float* pixb = (const float*)d_in[2];
    const float* paw  = (const float*)d_in[3];
    const float* pab  = (const float*)d_in[4];
    float* ws  = (float*)d_ws;
    float* out = (float*)d_out;

    hipLaunchKernelGGL(k_prep,  dim3(582), dim3(256), 0, stream, x, paw, ws);
    hipLaunchKernelGGL(k_gemm,  dim3(588), dim3(256), 0, stream,
                       pixw, pixb, pab, ws);
    hipLaunchKernelGGL(k_pixel, dim3(392), dim3(256), 0, stream,
                       x, pixw, pixb, ws, out);
}

// Round 11
// 50.755 us; speedup vs baseline: 1.0925x; 1.0925x over previous
//
#include <hip/hip_runtime.h>
#include <math.h>

#define EPS 1e-8f
#define NPATCH 196
#define HW 50176
#define LOG2E 1.4426950408889634f

// ws float offsets — main path
#define GRAM_OFF 0        // 10
#define P5_OFF 64         // 48*784        (norm^2 partials)   [mtile][patch]
#define DJ_OFF 38400      // 48*784*4      (basis-dot partials)[mtile][patch][4]
#define GQ_OFF 188928     // 784*4
#define PART_OFF 192064   // 784
#define WA_OFF 196608     // bf16[768*768] = 294912 float slots
#define XPB_OFF 491520    // bf16[784*768] = 301056 float slots
#define WS_NEED ((size_t)(XPB_OFF + 301056 + 64) * 4)
// fallback-only offsets (never coexist with P5/DJ use)
#define C_OFF 12          // 4
#define N2_OFF 64         // 784
#define M_OFF 1024        // 768*4

typedef __attribute__((ext_vector_type(8))) short short8;
typedef __attribute__((ext_vector_type(4))) float f32x4;

static __device__ __forceinline__ unsigned short f2bf(float f) {
    unsigned u = __float_as_uint(f);
    u += 0x8000u + ((u >> 16) & 1u);     // RNE
    return (unsigned short)(u >> 16);
}

// ---------------- main-path prep: pure streaming ----------------
// blocks 0..287   : WA = bf16(paw), 8 elems/thread
// blocks 288..581 : XPB = bf16(gathered x-patches), 8 elems/thread
// block 582       : gram (10 floats)
__global__ __launch_bounds__(256) void k_prep(const float* __restrict__ x,
                                              const float* __restrict__ pixw,
                                              const float* __restrict__ pixb,
                                              const float* __restrict__ paw,
                                              float* __restrict__ ws) {
    int t = threadIdx.x;
    int bid = blockIdx.x;
    if (bid < 288) {
        int f8 = bid * 256 + t;                    // 0..73727
        const float4* src = (const float4*)paw + (size_t)f8 * 2;
        float4 a = src[0], b = src[1];
        short8 o;
        o[0] = f2bf(a.x); o[1] = f2bf(a.y); o[2] = f2bf(a.z); o[3] = f2bf(a.w);
        o[4] = f2bf(b.x); o[5] = f2bf(b.y); o[6] = f2bf(b.z); o[7] = f2bf(b.w);
        *(short8*)((unsigned short*)(ws + WA_OFF) + (size_t)f8 * 8) = o;
    } else if (bid < 582) {
        int f8 = (bid - 288) * 256 + t;            // 0..75263
        int gp = f8 / 96;                          // 96 8-chunks per patch
        int e = (f8 - gp * 96) * 8;
        int b = gp / NPATCH, m = gp - b * NPATCH;
        int hp = m / 14, wq = m - hp * 14;
        int c = e >> 8, rem = e & 255, pr = rem >> 4, q0 = rem & 15;
        const float* src = x + ((size_t)(b * 3 + c) * 224 + hp * 16 + pr) * 224
                             + wq * 16 + q0;
        float4 a = *(const float4*)src;
        float4 b2 = *(const float4*)(src + 4);
        short8 o;
        o[0] = f2bf(a.x); o[1] = f2bf(a.y); o[2] = f2bf(a.z); o[3] = f2bf(a.w);
        o[4] = f2bf(b2.x); o[5] = f2bf(b2.y); o[6] = f2bf(b2.z); o[7] = f2bf(b2.w);
        *(short8*)((unsigned short*)(ws + XPB_OFF) + (size_t)gp * 768 + e) = o;
    } else {
        __shared__ float lds[4 * 10];
        float g[10];
        #pragma unroll
        for (int j = 0; j < 10; ++j) g[j] = 0.f;
        #pragma unroll
        for (int dd = 0; dd < 3; ++dd) {
            int d = t + dd * 256;
            float w0 = pixw[d*3+0], w1 = pixw[d*3+1], w2 = pixw[d*3+2], b = pixb[d];
            g[0] = fmaf(w0, w0, g[0]); g[1] = fmaf(w0, w1, g[1]);
            g[2] = fmaf(w0, w2, g[2]); g[3] = fmaf(w0, b,  g[3]);
            g[4] = fmaf(w1, w1, g[4]); g[5] = fmaf(w1, w2, g[5]);
            g[6] = fmaf(w1, b,  g[6]); g[7] = fmaf(w2, w2, g[7]);
            g[8] = fmaf(w2, b,  g[8]); g[9] = fmaf(b,  b,  g[9]);
        }
        #pragma unroll
        for (int off = 32; off; off >>= 1)
            #pragma unroll
            for (int j = 0; j < 10; ++j) g[j] += __shfl_down(g[j], off);
        int wv = t >> 6, ln = t & 63;
        if (ln == 0)
            for (int j = 0; j < 10; ++j) lds[wv * 10 + j] = g[j];
        __syncthreads();
        if (t < 10)
            ws[GRAM_OFF + t] = lds[t] + lds[10 + t] + lds[20 + t] + lds[30 + t];
    }
}

// 588 blocks x 256 thr (4 waves). wave -> one 16x16 C tile; K=768 in 24 MFMA.
// Emits per-tile partials: P5 (sum v^2) and DJ[4] (sum basis_j * v).
__global__ __launch_bounds__(256) void k_gemm(const float* __restrict__ pixw,
                                              const float* __restrict__ pixb,
                                              const float* __restrict__ pab,
                                              float* __restrict__ ws) {
    const unsigned short* WA  = (const unsigned short*)(ws + WA_OFF);
    const unsigned short* XPB = (const unsigned short*)(ws + XPB_OFF);
    int t = threadIdx.x;
    int lane = t & 63;
    int wv = t >> 6;
    int bid = blockIdx.x;
    int msup = bid / 49;
    int ntile = bid - msup * 49;
    int mtile = msup * 4 + wv;
    int m0 = mtile * 16, n0 = ntile * 16;
    int ra = lane & 15, kg = lane >> 4;
    const short8* pa = (const short8*)(WA  + (size_t)(m0 + ra) * 768 + kg * 8);
    const short8* pb = (const short8*)(XPB + (size_t)(n0 + ra) * 768 + kg * 8);
    f32x4 acc = {0.f, 0.f, 0.f, 0.f};
    #pragma unroll 6
    for (int kk = 0; kk < 24; ++kk) {
        short8 a = pa[kk * 4];
        short8 b = pb[kk * 4];
        acc = __builtin_amdgcn_mfma_f32_16x16x32_bf16(a, b, acc, 0, 0, 0);
    }
    // C[row][col]: col = lane&15 (patch), row = kg*4 + i (dim within tile)
    float sq = 0.f, d0 = 0.f, d1 = 0.f, d2 = 0.f, d3 = 0.f;
    #pragma unroll
    for (int i = 0; i < 4; ++i) {
        int d = m0 + kg * 4 + i;
        float v = acc[i] + pab[d];
        sq = fmaf(v, v, sq);
        d0 = fmaf(pixw[d*3+0], v, d0);
        d1 = fmaf(pixw[d*3+1], v, d1);
        d2 = fmaf(pixw[d*3+2], v, d2);
        d3 = fmaf(pixb[d],     v, d3);
    }
    sq += __shfl_down(sq, 32); d0 += __shfl_down(d0, 32);
    d1 += __shfl_down(d1, 32); d2 += __shfl_down(d2, 32);
    d3 += __shfl_down(d3, 32);
    sq += __shfl_down(sq, 16); d0 += __shfl_down(d0, 16);
    d1 += __shfl_down(d1, 16); d2 += __shfl_down(d2, 16);
    d3 += __shfl_down(d3, 16);
    if (lane < 16) {
        int gp = n0 + lane;
        ws[P5_OFF + (size_t)mtile * 784 + gp] = sq;
        *(float4*)&ws[DJ_OFF + ((size_t)mtile * 784 + gp) * 4] =
            make_float4(d0, d1, d2, d3);
    }
}

// 49 blocks x 256: 16 patches/block, 16 lanes/patch. Gq = dj / ||v||.
__global__ __launch_bounds__(256) void k_final(float* __restrict__ ws) {
    int t = threadIdx.x;
    int pl = t >> 4, l = t & 15;
    int gp = blockIdx.x * 16 + pl;
    float n2 = 0.f, d0 = 0.f, d1 = 0.f, d2 = 0.f, d3 = 0.f;
    #pragma unroll
    for (int r = 0; r < 3; ++r) {
        int i = l + r * 16;
        n2 += ws[P5_OFF + (size_t)i * 784 + gp];
        float4 dv = *(const float4*)&ws[DJ_OFF + ((size_t)i * 784 + gp) * 4];
        d0 += dv.x; d1 += dv.y; d2 += dv.z; d3 += dv.w;
    }
    #pragma unroll
    for (int off = 8; off; off >>= 1) {
        n2 += __shfl_down(n2, off, 16);
        d0 += __shfl_down(d0, off, 16); d1 += __shfl_down(d1, off, 16);
        d2 += __shfl_down(d2, off, 16); d3 += __shfl_down(d3, off, 16);
    }
    if (l == 0) {
        float rq = 1.0f / fmaxf(sqrtf(n2), EPS);
        *(float4*)&ws[GQ_OFF + gp * 4] = make_float4(d0*rq, d1*rq, d2*rq, d3*rq);
    }
}

__global__ __launch_bounds__(256) void k_pixel(const float* __restrict__ x,
                                               float* __restrict__ ws) {
    int t = threadIdx.x;
    int bid = blockIdx.x;
    int b = bid / NPATCH, loc = bid - b * NPATCH;
    int hw = loc * 256 + t;
    const float* xb = x + (size_t)b * (3 * HW);
    float c0 = xb[hw], c1 = xb[hw + HW], c2 = xb[hw + 2 * HW];

    float G0 = ws[0], G1 = ws[1], G2 = ws[2], G3 = ws[3], G4 = ws[4];
    float G5 = ws[5], G6 = ws[6], G7 = ws[7], G8 = ws[8], G9 = ws[9];
    float n2 = G9;
    n2 = fmaf(G0, c0 * c0, n2);
    n2 = fmaf(G4, c1 * c1, n2);
    n2 = fmaf(G7, c2 * c2, n2);
    float cross = fmaf(G1, c0 * c1, fmaf(G2, c0 * c2, fmaf(G5, c1 * c2,
                  fmaf(G3, c0, fmaf(G6, c1, G8 * c2)))));
    n2 = fmaf(2.0f, cross, n2);

    float rnp = 1.0f / fmaxf(sqrtf(n2), EPS);
    float es = 2.0f * rnp * LOG2E;
    float a0 = c0 * es, a1 = c1 * es, a2 = c2 * es;

    const float4* gq = (const float4*)(ws + GQ_OFF) + b * NPATCH;
    float sum = 0.0f;
    #pragma unroll 4
    for (int m = 0; m < NPATCH; ++m) {
        float4 g = gq[m];
        float tt = fmaf(a0, g.x, fmaf(a1, g.y, fmaf(a2, g.z, es * g.w)));
        sum += __builtin_amdgcn_exp2f(tt);
    }
    {
        int ne = hw % NPATCH;
        float4 g = gq[ne];
        float tt = fmaf(a0, g.x, fmaf(a1, g.y, fmaf(a2, g.z, es * g.w)));
        sum -= __builtin_amdgcn_exp2f(tt);
    }

    #pragma unroll
    for (int off = 32; off; off >>= 1) sum += __shfl_down(sum, off);
    __shared__ float red[4];
    int wvv = t >> 6, ln = t & 63;
    if (ln == 0) red[wvv] = sum;
    __syncthreads();
    if (t == 0) ws[PART_OFF + bid] = red[0] + red[1] + red[2] + red[3];
}

__global__ __launch_bounds__(256) void k_log(const float* __restrict__ ws,
                                             float* __restrict__ out) {
    int t = threadIdx.x;
    float sum = 0.0f;
    for (int j = t; j < 784; j += 256) sum += ws[PART_OFF + j];
    #pragma unroll
    for (int off = 32; off; off >>= 1) sum += __shfl_down(sum, off);
    __shared__ float red[4];
    int wv = t >> 6, ln = t & 63;
    if (ln == 0) red[wv] = sum;
    __syncthreads();
    if (t == 0) out[0] = logf(red[0] + red[1] + red[2] + red[3]);
}

// ---------------- fallback path (tiny ws): M + c, f32 norms ----------------
__global__ __launch_bounds__(512) void k_prep_fb(const float* __restrict__ pixw,
                                                 const float* __restrict__ pixb,
                                                 const float* __restrict__ paw,
                                                 const float* __restrict__ pab,
                                                 float* __restrict__ ws) {
    __shared__ float lds[2048];
    int t = threadIdx.x;
    int bid = blockIdx.x;
    if (bid < 12) {
        int lane = t & 63;
        int dh = t >> 6;
        int k = bid * 64 + lane;
        float m0 = 0.f, m1 = 0.f, m2 = 0.f, m3 = 0.f;
        #pragma unroll 4
        for (int i = 0; i < 96; ++i) {
            int d = dh * 96 + i;
            float w = paw[(size_t)d * 768 + k];
            m0 = fmaf(pixw[d*3+0], w, m0); m1 = fmaf(pixw[d*3+1], w, m1);
            m2 = fmaf(pixw[d*3+2], w, m2); m3 = fmaf(pixb[d], w, m3);
        }
        float* L = lds + (dh * 64 + lane) * 4;
        L[0] = m0; L[1] = m1; L[2] = m2; L[3] = m3;
        __syncthreads();
        if (t < 64) {
            float4 o = make_float4(0.f, 0.f, 0.f, 0.f);
            #pragma unroll
            for (int g = 0; g < 8; ++g) {
                const float* p = lds + (g * 64 + t) * 4;
                o.x += p[0]; o.y += p[1]; o.z += p[2]; o.w += p[3];
            }
            *(float4*)&ws[M_OFF + (bid * 64 + t) * 4] = o;
        }
    } else {
        float g[14];
        #pragma unroll
        for (int j = 0; j < 14; ++j) g[j] = 0.f;
        for (int d = t; d < 768; d += 512) {
            float w0 = pixw[d*3+0], w1 = pixw[d*3+1], w2 = pixw[d*3+2];
            float b = pixb[d], pb = pab[d];
            g[0] = fmaf(w0, w0, g[0]); g[1] = fmaf(w0, w1, g[1]);
            g[2] = fmaf(w0, w2, g[2]); g[3] = fmaf(w0, b,  g[3]);
            g[4] = fmaf(w1, w1, g[4]); g[5] = fmaf(w1, w2, g[5]);
            g[6] = fmaf(w1, b,  g[6]); g[7] = fmaf(w2, w2, g[7]);
            g[8] = fmaf(w2, b,  g[8]); g[9] = fmaf(b,  b,  g[9]);
            g[10] = fmaf(w0, pb, g[10]); g[11] = fmaf(w1, pb, g[11]);
            g[12] = fmaf(w2, pb, g[12]); g[13] = fmaf(b,  pb, g[13]);
        }
        #pragma unroll
        for (int off = 32; off; off >>= 1)
            #pragma unroll
            for (int j = 0; j < 14; ++j) g[j] += __shfl_down(g[j], off);
        int wv = t >> 6, ln = t & 63;
        if (ln == 0)
            for (int j = 0; j < 14; ++j) lds[wv * 14 + j] = g[j];
        __syncthreads();
        if (t < 14) {
            float s = 0.f;
            for (int w = 0; w < 8; ++w) s += lds[w * 14 + t];
            if (t < 10) ws[GRAM_OFF + t] = s;
            else        ws[C_OFF + (t - 10)] = s;
        }
    }
}

__global__ __launch_bounds__(512, 2) void k_n2_fb(const float* __restrict__ x,
                                                  const float* __restrict__ paw,
                                                  const float* __restrict__ pab,
                                                  float* __restrict__ ws) {
    __shared__ float lds[4 * 64 * 13];
    __shared__ float red2[4][4];
    int t = threadIdx.x;
    int lane = t & 63;
    int wv = __builtin_amdgcn_readfirstlane(t >> 6);
    int dw = wv & 3, kh = wv >> 2;
    int pg = blockIdx.x;
    const float* xbp[4];
    #pragma unroll
    for (int pp = 0; pp < 4; ++pp) {
        int gp = pg * 4 + pp;
        int b = gp / NPATCH, m = gp - b * NPATCH;
        int hp = m / 14, wq = m - hp * 14;
        xbp[pp] = x + (size_t)b * (3 * HW) + (hp * 16) * 224 + wq * 16;
    }
    int d0 = dw * 192 + lane;
    float acc[3][4];
    #pragma unroll
    for (int i = 0; i < 3; ++i)
        #pragma unroll
        for (int p = 0; p < 4; ++p) acc[i][p] = 0.f;
    int r0 = kh * 24;
    #pragma unroll 2
    for (int r = r0; r < r0 + 24; ++r) {
        int c = r >> 4, pr = r & 15, kb = r * 16;
        #pragma unroll
        for (int qh = 0; qh < 2; ++qh) {
            float wf[3][8];
            #pragma unroll
            for (int dd = 0; dd < 3; ++dd) {
                const float* wrow = paw + (size_t)(d0 + dd * 64) * 768 + kb + qh * 8;
                float4 a = *(const float4*)(wrow);
                float4 b2 = *(const float4*)(wrow + 4);
                wf[dd][0] = a.x; wf[dd][1] = a.y; wf[dd][2] = a.z; wf[dd][3] = a.w;
                wf[dd][4] = b2.x; wf[dd][5] = b2.y; wf[dd][6] = b2.z; wf[dd][7] = b2.w;
            }
            #pragma unroll
            for (int q = 0; q < 8; ++q) {
                #pragma unroll
                for (int p = 0; p < 4; ++p) {
                    float xv = xbp[p][c * HW + pr * 224 + qh * 8 + q];
                    #pragma unroll
                    for (int dd = 0; dd < 3; ++dd)
                        acc[dd][p] = fmaf(wf[dd][q], xv, acc[dd][p]);
                }
            }
        }
    }
    if (kh == 1) {
        float* L = lds + (dw * 64 + lane) * 13;
        #pragma unroll
        for (int i = 0; i < 3; ++i)
            #pragma unroll
            for (int p = 0; p < 4; ++p) L[i * 4 + p] = acc[i][p];
    }
    __syncthreads();
    if (kh == 0) {
        const float* L = lds + (dw * 64 + lane) * 13;
        float sq[4] = {0.f, 0.f, 0.f, 0.f};
        #pragma unroll
        for (int i = 0; i < 3; ++i) {
            float bias = pab[d0 + i * 64];
            #pragma unroll
            for (int p = 0; p < 4; ++p) {
                float v = acc[i][p] + L[i * 4 + p] + bias;
                sq[p] = fmaf(v, v, sq[p]);
            }
        }
        #pragma unroll
        for (int off = 32; off; off >>= 1)
            #pragma unroll
            for (int p = 0; p < 4; ++p) sq[p] += __shfl_down(sq[p], off);
        if (lane == 0)
            for (int p = 0; p < 4; ++p) red2[dw][p] = sq[p];
    }
    __syncthreads();
    if (t < 4)
        ws[N2_OFF + pg * 4 + t] = red2[0][t] + red2[1][t] + red2[2][t] + red2[3][t];
}

__global__ __launch_bounds__(256) void k_dj_fb(const float* __restrict__ x,
                                               float* __restrict__ ws) {
    int t = threadIdx.x;
    int p8 = t >> 5, l = t & 31;
    int gp = blockIdx.x * 8 + p8;
    int b = gp / NPATCH, m = gp - b * NPATCH;
    int hp = m / 14, wq = m - hp * 14;
    const float* xb = x + (size_t)b * (3 * HW) + (hp * 16) * 224 + wq * 16;
    float d0 = 0.f, d1 = 0.f, d2 = 0.f, d3 = 0.f;
    #pragma unroll 4
    for (int j = 0; j < 24; ++j) {
        int k = j * 32 + l;
        int c = k >> 8, pr = (k >> 4) & 15, q = k & 15;
        float xv = xb[c * HW + pr * 224 + q];
        float4 Mv = *(const float4*)&ws[M_OFF + k * 4];
        d0 = fmaf(Mv.x, xv, d0); d1 = fmaf(Mv.y, xv, d1);
        d2 = fmaf(Mv.z, xv, d2); d3 = fmaf(Mv.w, xv, d3);
    }
    #pragma unroll
    for (int off = 16; off; off >>= 1) {
        d0 += __shfl_down(d0, off, 32); d1 += __shfl_down(d1, off, 32);
        d2 += __shfl_down(d2, off, 32); d3 += __shfl_down(d3, off, 32);
    }
    if (l == 0) {
        float n2 = ws[N2_OFF + gp];
        float rq = 1.0f / fmaxf(sqrtf(n2), EPS);
        float4 o;
        o.x = (d0 + ws[C_OFF + 0]) * rq;
        o.y = (d1 + ws[C_OFF + 1]) * rq;
        o.z = (d2 + ws[C_OFF + 2]) * rq;
        o.w = (d3 + ws[C_OFF + 3]) * rq;
        *(float4*)&ws[GQ_OFF + gp * 4] = o;
    }
}

extern "C" void kernel_launch(void* const* d_in, const int* in_sizes, int n_in,
                              void* d_out, int out_size, void* d_ws, size_t ws_size,
                              hipStream_t stream) {
    (void)in_sizes; (void)n_in; (void)out_size;
    const float* x    = (const float*)d_in[0];
    const float* pixw = (const float*)d_in[1];
    const float* pixb = (const float*)d_in[2];
    const float* paw  = (const float*)d_in[3];
    const float* pab  = (const float*)d_in[4];
    float* ws  = (float*)d_ws;
    float* out = (float*)d_out;

    if (ws_size >= WS_NEED) {
        hipLaunchKernelGGL(k_prep,  dim3(583), dim3(256), 0, stream, x, pixw, pixb, paw, ws);
        hipLaunchKernelGGL(k_gemm,  dim3(588), dim3(256), 0, stream, pixw, pixb, pab, ws);
        hipLaunchKernelGGL(k_final, dim3(49),  dim3(256), 0, stream, ws);
    } else {
        hipLaunchKernelGGL(k_prep_fb, dim3(13),  dim3(512), 0, stream, pixw, pixb, paw, pab, ws);
        hipLaunchKernelGGL(k_n2_fb,   dim3(196), dim3(512), 0, stream, x, paw, pab, ws);
        hipLaunchKernelGGL(k_dj_fb,   dim3(98),  dim3(256), 0, stream, x, ws);
    }
    hipLaunchKernelGGL(k_pixel, dim3(784), dim3(256), 0, stream, x, ws);
    hipLaunchKernelGGL(k_log,   dim3(1),   dim3(256), 0, stream, ws, out);
}